// Round 5
// baseline (2174.859 us; speedup 1.0000x reference)
//
#include <hip/hip_runtime.h>
#include <math.h>

// Problem constants: B=8192, S=2TX=64, F=65, HID=128, 3H=384, DIMZ=64, DIRS=2
// GD_STEP=1e-6 (two_step=2e-6), GD_ITERS=10, BN_EPS=1e-5

typedef __attribute__((ext_vector_type(8))) short s8v;   // 8 x bf16 (MFMA A/B frag)
typedef __attribute__((ext_vector_type(4))) float f4v;   // MFMA C/D frag

__device__ __forceinline__ short f2bf(float x) {         // RNE float->bf16
  unsigned u = __float_as_uint(x);
  u += 0x7fffu + ((u >> 16) & 1u);
  return (short)(u >> 16);
}
__device__ __forceinline__ float bf2f(short h) {
  return __uint_as_float(((unsigned)(unsigned short)h) << 16);
}
__device__ __forceinline__ void fma4(float4& c, float a, const float4 w) {
  c.x += a*w.x; c.y += a*w.y; c.z += a*w.z; c.w += a*w.w;
}
__device__ __forceinline__ float vget(const float4& v, int i) { return ((const float*)&v)[i]; }

// async global->LDS, 16B/lane; dest is wave-uniform base (+lane*16 by HW)
__device__ __forceinline__ void gload16(const void* g, void* l) {
  __builtin_amdgcn_global_load_lds(
      (const __attribute__((address_space(1))) void*)g,
      (__attribute__((address_space(3))) void*)l, 16, 0, 0);
}

#define MFMA(A, B, C) __builtin_amdgcn_mfma_f32_16x16x32_bf16((A), (B), (C), 0, 0, 0)

// ---------------------------------------------------------------------------
// K1: per-batch HtH -> UNSCALED split-bf16 fragX (A-frag order), htyU[s][b],
// BN stat partials. fragX elem (b,s,k): tile=b>>6, mt=(b>>4)&3, chunk kt=k>>5,
// lane=(b&15)+16*((k>>3)&3), i=k&7; hi at chunk*512+lane*8+i, lo at +4096.
// ---------------------------------------------------------------------------
__global__ __launch_bounds__(256) void k_feats(
    const float* __restrict__ Hm, const float* __restrict__ y,
    short* __restrict__ fragX, float* __restrict__ htyU, float* __restrict__ bnacc)
{
  __shared__ __align__(16) float Hl[64][68];
  __shared__ float yl[64];
  __shared__ float s1[64], s2[64];
  const int b = blockIdx.x;
  const int tid = threadIdx.x;
  const float* Hb = Hm + (size_t)b*4096;
  for (int i = tid; i < 4096; i += 256) Hl[i>>6][i&63] = Hb[i];
  if (tid < 64) { yl[tid] = y[b*64+tid]; s1[tid] = 0.f; s2[tid] = 0.f; }
  __syncthreads();

  if (tid < 64) {                       // Hty channel (f=64), unscaled, [s][b]
    float acc = 0.f;
    for (int r = 0; r < 64; ++r) acc += Hl[r][tid]*yl[r];
    htyU[tid*8192 + b] = acc;
    atomicAdd(&s1[tid], acc);
    atomicAdd(&s2[tid], acc*acc);
  }
  const int tg = tid & 15, ug = tid >> 4;
  float4 acc4[4];
  acc4[0]=acc4[1]=acc4[2]=acc4[3]=make_float4(0.f,0.f,0.f,0.f);
  for (int r = 0; r < 64; ++r) {        // HtH[t=4tg+tt][u=4ug+uu]
    const float4 tv = *(const float4*)&Hl[r][4*tg];
    const float4 uv = *(const float4*)&Hl[r][4*ug];
    #pragma unroll
    for (int tt=0;tt<4;++tt) fma4(acc4[tt], vget(tv,tt), uv);
  }
  // frag-store geometry (u = 4ug..4ug+3 -> 4 consecutive shorts in one group)
  const int mt   = (b >> 4) & 3;
  const int brow = b & 15;
  const int u0   = 4*ug;
  short* fbase = fragX + (size_t)(b >> 6)*64*8192
               + (mt*2 + (u0 >> 5))*512 + (brow + 16*((u0 >> 3) & 3))*8 + (u0 & 7);
  #pragma unroll
  for (int tt=0;tt<4;++tt) {
    const int t = 4*tg+tt;              // t == seq channel s
    float sv=0.f, sq=0.f;
    short hib[4], lob[4];
    #pragma unroll
    for (int uu=0;uu<4;++uu) {
      const float v = vget(acc4[tt],uu);
      const short hi = f2bf(v);
      hib[uu] = hi; lob[uu] = f2bf(v - bf2f(hi));
      sv += v; sq += v*v;
    }
    short* dst = fbase + (size_t)t*8192;
    *(short4*)dst          = make_short4(hib[0],hib[1],hib[2],hib[3]);
    *(short4*)(dst + 4096) = make_short4(lob[0],lob[1],lob[2],lob[3]);
    sv += __shfl_down(sv,32); sq += __shfl_down(sq,32);
    sv += __shfl_down(sv,16); sq += __shfl_down(sq,16);
    if ((tid & 63) < 16) { atomicAdd(&s1[t], sv); atomicAdd(&s2[t], sq); }
  }
  __syncthreads();
  if (tid < 64) {
    atomicAdd(&bnacc[tid*16],      s1[tid]);
    atomicAdd(&bnacc[(64+tid)*16], s2[tid]);
  }
}

// ---------------------------------------------------------------------------
// K2a: BN finalize -> a[t]=gamma/sqrt(var+eps), c[t]=beta-mu*a
// ---------------------------------------------------------------------------
__global__ void k_bnfin(const float* __restrict__ bnacc, const float* __restrict__ gam,
                        const float* __restrict__ bet, float* __restrict__ bnac)
{
  const int t = threadIdx.x;
  if (t < 64) {
    const float inv = 1.f/532480.f;           // B*F = 8192*65
    const float mu  = bnacc[t*16]*inv;
    const float var = bnacc[(64+t)*16]*inv - mu*mu;
    const float a = gam[t]*rsqrtf(var + 1e-5f);
    bnac[t] = a;
    bnac[64+t] = bet[t] - mu*a;
  }
}

// ---------------------------------------------------------------------------
// K2b: split-bf16 weight images in MFMA B-frag order + wih row sums
// Wg:  [d][sp][nt(24)][kt(6)][512]  (k: 0..63=f(wih), 64..191=j(whh))
// W2g: [d][sp][nt2(8)][kt(4)][512]  (n2: 0..63=Wx row, 64..127=Wz row)
// ---------------------------------------------------------------------------
__global__ __launch_bounds__(256) void k_prep(
    const float* __restrict__ wih, const float* __restrict__ whh,
    const float* __restrict__ Wz, const float* __restrict__ Wx,
    short* __restrict__ Wg, short* __restrict__ W2g, float* __restrict__ rowsum)
{
  const int i = blockIdx.x*256 + threadIdx.x;
  if (i < 294912) {
    const int dd = i / 147456, r = i % 147456;
    const int sp = r / 73728, r2 = r % 73728;
    const int chunk = r2 / 512, e = r2 % 512;
    const int lane = e >> 3, ii = e & 7;
    const int nt = chunk / 6, kt = chunk % 6;
    const int n = nt*16 + (lane & 15);
    const int k = kt*32 + (lane >> 4)*8 + ii;
    const float v = (k < 64) ? wih[dd*24960 + n*65 + k]
                             : whh[dd*49152 + n*128 + (k - 64)];
    const short hi = f2bf(v);
    Wg[i] = sp ? f2bf(v - bf2f(hi)) : hi;
  } else if (i < 360448) {
    const int t = i - 294912;
    const int dd = t / 32768, r = t % 32768;
    const int sp = r / 16384, r2 = r % 16384;
    const int chunk = r2 / 512, e = r2 % 512;
    const int lane = e >> 3, ii = e & 7;
    const int nt2 = chunk / 4, kt = chunk % 4;
    const int n2 = nt2*16 + (lane & 15);
    const int k = kt*32 + (lane >> 4)*8 + ii;
    const float v = (n2 < 64) ? Wx[n2*256 + dd*128 + k]
                              : Wz[(n2 - 64)*256 + dd*128 + k];
    const short hi = f2bf(v);
    W2g[t] = sp ? f2bf(v - bf2f(hi)) : hi;
  } else if (i < 361216) {
    const int t = i - 360448;
    const int dd = t / 384, g = t % 384;
    float ssum = 0.f;
    for (int f = 0; f < 65; ++f) ssum += wih[dd*24960 + g*65 + f];
    rowsum[t] = ssum;
  }
}

// ---------------------------------------------------------------------------
// K3: GRU scan. ROUND-5: OCCUPANCY DOUBLING.
// Block = 32 batches x 1 dir (was 64), grid 512 (was 256) -> 2 blocks/CU.
// Evidence: 4 rounds invariant at Occupancy 23% (1 block/CU, 2 waves/SIMD),
// no pipe >31% busy, per-step wall ~50k cyc vs ~8k issue -> latency-bound
// from lack of co-resident work. Independent co-resident blocks hide ANY
// stall source (LDS dep, exp chain, barrier skew, L2 latency).
// Wave w still owns gate cols {j,128+j,256+j : j=16w+l15}; M-frags mtl=0..1.
// fragX half-tile addressing: T64=tile>>1, hh=tile&1, mt64=2*hh+mtl.
// Structure = proven round-3 single-__syncthreads loop (no inline asm).
// LDS/block: Ax 16K + Ah 32K + xl 9K + gcl 6K + z0l 8.5K + bna .5K = 72 KB.
// ---------------------------------------------------------------------------
__global__ __launch_bounds__(512, 2) void k_scan(
    const short* __restrict__ fragX, const float* __restrict__ htyU,
    const float* __restrict__ xraw,
    const short* __restrict__ Wg, const short* __restrict__ W2g,
    const float* __restrict__ bih, const float* __restrict__ bhh,
    const float* __restrict__ rowsum, const float* __restrict__ bnac,
    const float* __restrict__ wih,
    float* __restrict__ wx_out, float* __restrict__ z0_out)
{
  __shared__ __align__(16) short Axb[8192];   // 2 x [sp(2)][mtl(2)][kt(2)][512]
  __shared__ __align__(16) short Ahb[16384];  // 2 x [sp(2)][mtl(2)][kth(4)][512]
  __shared__ __align__(16) float xl[64][36];  // 2*xraw-3, [s][b_local(32)+pad]
  __shared__ __align__(16) float gcl[1536];   // per-j consts: [j(128)][12]
  __shared__ __align__(16) float z0l[32][68]; // z0 accum [b_local][col]
  __shared__ float bna[128];

  const int tid = threadIdx.x;
  const int l   = tid & 63;
  const int w   = __builtin_amdgcn_readfirstlane(tid >> 6);   // wave 0..7
  const int tile = blockIdx.x >> 1, d = blockIdx.x & 1;       // tile 0..255
  const int b0  = tile * 32;
  const int T64 = tile >> 1, hh = tile & 1;                   // 64-tile, half
  const int l15 = l & 15, lq = l >> 4;
  const int j   = 16*w + l15;                 // this lane's hidden unit
  const int zcol = 16*(w & 3) + l15;          // z0 col for waves 4-7

  const short* Wgd = Wg  + d*147456;
  const short* W2d = W2g + d*32768;
  float* wxo = wx_out + (size_t)d * (8192ull*4096ull);
  float* z0o = z0_out + (size_t)d * (8192ull*64ull);

  // ---- persistent weight fragments (VGPR/AGPR-resident), unchanged ----
  s8v BR[6][2], BZ[6][2], BN[6][2], BP[4][2];
  #pragma unroll
  for (int kt = 0; kt < 6; ++kt)
    #pragma unroll
    for (int sp = 0; sp < 2; ++sp) {
      BR[kt][sp] = *(const s8v*)&Wgd[((sp*24 + w     )*6 + kt)*512 + l*8];
      BZ[kt][sp] = *(const s8v*)&Wgd[((sp*24 + 8 + w )*6 + kt)*512 + l*8];
      BN[kt][sp] = *(const s8v*)&Wgd[((sp*24 + 16 + w)*6 + kt)*512 + l*8];
    }
  #pragma unroll
  for (int kt = 0; kt < 4; ++kt)
    #pragma unroll
    for (int sp = 0; sp < 2; ++sp)
      BP[kt][sp] = *(const s8v*)&W2d[((sp*8 + w)*4 + kt)*512 + l*8];

  // h-write geometry: value (m16=lq*4+e in mtl group, col j) -> A-frag slot
  const int hw_base = (j >> 5)*512 + ((j >> 3) & 3)*128 + (j & 7);

  // this wave's staging chunk: w -> (sp, mtl, kt); byte offset inside fragX[s]
  const int c_sp  = w >> 2, c_mtl = (w >> 1) & 1, c_kt = w & 1;
  const size_t choff = (size_t)c_sp*8192 + (size_t)(2*(2*hh + c_mtl) + c_kt)*1024;
  const char* fragT = (const char*)fragX + (size_t)T64*1048576ull;

  // ---- one-time LDS preloads ----
  for (int i = tid; i < 16384; i += 512) Ahb[i] = 0;
  for (int i = tid; i < 2048; i += 512) {       // coalesced: s fastest
    const int bl = i >> 6, s = i & 63;
    xl[s][bl] = 2.f*xraw[(size_t)(b0 + bl)*64 + s] - 3.f;   // 2x - 2^RATE + 1
  }
  if (tid < 128) {                              // gate-constant table (once)
    const int jj = tid;
    float* g = &gcl[jj*12];
    g[0] = rowsum[d*384 + jj];
    g[1] = rowsum[d*384 + 128 + jj];
    g[2] = rowsum[d*384 + 256 + jj];
    g[3] = bih[d*384 + jj]       + bhh[d*384 + jj];
    g[4] = bih[d*384 + 128 + jj] + bhh[d*384 + 128 + jj];
    g[5] = bih[d*384 + 256 + jj];
    g[6] = bhh[d*384 + 256 + jj];
    g[7] = wih[d*24960 + jj*65 + 64];           // f=64 (Hty) column weights
    g[8] = wih[d*24960 + (128 + jj)*65 + 64];
    g[9] = wih[d*24960 + (256 + jj)*65 + 64];
    g[10] = 0.f; g[11] = 0.f;
  }
  for (int i = tid; i < 32*68; i += 512) ((float*)z0l)[i] = 0.f;
  if (tid < 128) bna[tid] = bnac[tid];

  f4v hprev[2];
  hprev[0] = (f4v)0.f; hprev[1] = (f4v)0.f;

  {   // prologue: Ax(s_first) -> buffer 0 (each wave loads its 1KB chunk)
    const int s0 = d ? 63 : 0;
    gload16(fragT + (size_t)s0*16384 + choff + l*16, (char*)Axb + w*1024);
  }
  __syncthreads();

  for (int it = 0; it < 64; ++it) {
    const int s  = d ? 63 - it : it;
    const int sn = (it < 63) ? (d ? s - 1 : s + 1) : s;

    const short* AxR = Axb + ((it & 1) << 12);        // X(s)   : read (4096 sh)
    char*        AxW = (char*)Axb + (((it + 1) & 1) << 13);   // X(s+1) fill
    const short* AhR = Ahb + (((it + 1) & 1) << 13);  // h(s-1) : read (8192 sh)
    short*       AhW = Ahb + ((it & 1) << 13);        // h(s)   : write + proj

    // async prefetch next step's Ax chunk (drained by this step's barrier)
    gload16(fragT + (size_t)sn*16384 + choff + l*16, AxW + w*1024);

    // per-step constants (volatile LDS reads: kept out of persistent regs)
    const float a_s = bna[s], c_s = bna[64 + s];
    const volatile float* gj = gcl + j*12;
    const float crK  = c_s*gj[0] + gj[3];
    const float czK  = c_s*gj[1] + gj[4];
    const float cnK  = c_s*gj[2] + gj[5];
    const float BHN  = gj[6];
    const float w64r = gj[7], w64z = gj[8], w64n = gj[9];

    // ---- gate GEMM + gates, per M-frag ----
    #pragma unroll
    for (int mtl = 0; mtl < 2; ++mtl) {
      // Hty rank-1 operand (L2-resident), issued before the MFMA block
      const float4 av4 = *(const float4*)&htyU[s*8192 + b0 + mtl*16 + lq*4];
      f4v Crx = (f4v)0.f, Czx = (f4v)0.f, Cnx = (f4v)0.f;
      f4v Crh = (f4v)0.f, Czh = (f4v)0.f, Cnh = (f4v)0.f;
      #pragma unroll
      for (int kt = 0; kt < 2; ++kt) {        // x part (K=64, unscaled)
        const s8v axh = *(const s8v*)&AxR[mtl*1024 + kt*512 + l*8];
        const s8v axl = *(const s8v*)&AxR[2048 + mtl*1024 + kt*512 + l*8];
        Crx = MFMA(axh, BR[kt][0], Crx); Crx = MFMA(axh, BR[kt][1], Crx); Crx = MFMA(axl, BR[kt][0], Crx);
        Czx = MFMA(axh, BZ[kt][0], Czx); Czx = MFMA(axh, BZ[kt][1], Czx); Czx = MFMA(axl, BZ[kt][0], Czx);
        Cnx = MFMA(axh, BN[kt][0], Cnx); Cnx = MFMA(axh, BN[kt][1], Cnx); Cnx = MFMA(axl, BN[kt][0], Cnx);
      }
      #pragma unroll
      for (int kh = 0; kh < 4; ++kh) {        // h part (K=128)
        const s8v ahh = *(const s8v*)&AhR[mtl*2048 + kh*512 + l*8];
        const s8v ahl = *(const s8v*)&AhR[4096 + mtl*2048 + kh*512 + l*8];
        const int kt = 2 + kh;
        Crh = MFMA(ahh, BR[kt][0], Crh); Crh = MFMA(ahh, BR[kt][1], Crh); Crh = MFMA(ahl, BR[kt][0], Crh);
        Czh = MFMA(ahh, BZ[kt][0], Czh); Czh = MFMA(ahh, BZ[kt][1], Czh); Czh = MFMA(ahl, BZ[kt][0], Czh);
        Cnh = MFMA(ahh, BN[kt][0], Cnh); Cnh = MFMA(ahh, BN[kt][1], Cnh); Cnh = MFMA(ahl, BN[kt][0], Cnh);
      }
      // exact fp32 rank-1 for the Hty channel (joins x-part, pre-a_s)
      f4v av; av[0]=av4.x; av[1]=av4.y; av[2]=av4.z; av[3]=av4.w;
      Crx += av * w64r; Czx += av * w64z; Cnx += av * w64n;
      // gates: r=sig, z=sig, n=tanh(xn + r*hn); BN scale a_s applied here
      #pragma unroll
      for (int e = 0; e < 4; ++e) {
        const float rr  = 1.f/(1.f + __expf(-(a_s*Crx[e] + Crh[e] + crK)));
        const float zz  = 1.f/(1.f + __expf(-(a_s*Czx[e] + Czh[e] + czK)));
        const float pre = a_s*Cnx[e] + cnK + rr*(Cnh[e] + BHN);
        const float ax2 = fabsf(pre);
        const float ee  = __expf(-2.f*ax2);
        const float nn  = copysignf((1.f - ee)/(1.f + ee), pre);
        hprev[mtl][e] = (1.f - zz)*nn + zz*hprev[mtl][e];
      }
    }

    // write h(s) hi/lo into AhW (double-buffered: no read-drain needed)
    #pragma unroll
    for (int mtl = 0; mtl < 2; ++mtl)
      #pragma unroll
      for (int e = 0; e < 4; ++e) {
        const float hv = hprev[mtl][e];
        const short hi = f2bf(hv);
        const int ad = mtl*2048 + hw_base + (lq*4 + e)*8;
        AhW[ad] = hi;
        AhW[4096 + ad] = f2bf(hv - bf2f(hi));
      }
    __syncthreads();   // ONE barrier/step: h(s) + async Ax(s+1) visible

    // ---- projection: waves 0-3 -> wx cols, waves 4-7 -> z0l accum ----
    #pragma unroll
    for (int mtl = 0; mtl < 2; ++mtl) {
      f4v Cp = (f4v)0.f;
      #pragma unroll
      for (int kt = 0; kt < 4; ++kt) {
        const s8v ahh = *(const s8v*)&AhW[mtl*2048 + kt*512 + l*8];
        const s8v ahl = *(const s8v*)&AhW[4096 + mtl*2048 + kt*512 + l*8];
        Cp = MFMA(ahh, BP[kt][0], Cp);
        Cp = MFMA(ahh, BP[kt][1], Cp);
        Cp = MFMA(ahl, BP[kt][0], Cp);
      }
      if (w < 4) {
        #pragma unroll
        for (int e = 0; e < 4; ++e)
          wxo[(size_t)(b0 + mtl*16 + lq*4 + e)*4096 + s*64 + 16*w + l15] = Cp[e];
      } else {
        #pragma unroll
        for (int e = 0; e < 4; ++e) {
          const int bl = mtl*16 + lq*4 + e;
          z0l[bl][zcol] += xl[s][bl] * Cp[e];   // LDS RMW, cols disjoint per wave
        }
      }
    }
  }
  if (w >= 4) {
    #pragma unroll
    for (int mtl = 0; mtl < 2; ++mtl)
      #pragma unroll
      for (int e = 0; e < 4; ++e) {
        const int bl = mtl*16 + lq*4 + e;
        z0o[(size_t)(b0 + bl)*64 + zcol] = z0l[bl][zcol];
      }
  }
}

// ---------------------------------------------------------------------------
// K4: GD loop via Gram trick: tmp=H@wx; ww=tmp^T tmp; wh=tmp^T y (no HtH).
// ---------------------------------------------------------------------------
__global__ __launch_bounds__(256) void k_gd(
    const float* __restrict__ Hm, const float* __restrict__ y,
    const float* __restrict__ wxf, const float* __restrict__ wxb,
    const float* __restrict__ z0f, const float* __restrict__ z0b,
    float* __restrict__ out)
{
  __shared__ __align__(16) float Hl[64][68];    // H[r][t]; reused as ww[zi][zj]
  __shared__ __align__(16) float wx[64][68];    // wx[s][z]
  __shared__ __align__(16) float tmp[64][68];   // (H@wx)[r][z]
  __shared__ float yl[64], wh[64], zv[64];
  const int b = blockIdx.x;
  const int tid = threadIdx.x;
  const float* Hb = Hm + (size_t)b*4096;
  for (int i = tid; i < 4096; i += 256) {
    Hl[i>>6][i&63] = Hb[i];
    wx[i>>6][i&63] = wxf[(size_t)b*4096 + i] + wxb[(size_t)b*4096 + i];
  }
  if (tid < 64) {
    yl[tid] = y[b*64+tid];
    zv[tid] = z0f[(size_t)b*64+tid] + z0b[(size_t)b*64+tid];
  }
  __syncthreads();
  const int zq = tid & 15, tq = tid >> 4;
  #pragma unroll
  for (int rr = 0; rr < 4; ++rr) {             // tmp = H @ wx
    const int r = 4*tq + rr;
    float4 a = make_float4(0.f,0.f,0.f,0.f);
    for (int t = 0; t < 64; ++t) fma4(a, Hl[r][t], *(const float4*)&wx[t][4*zq]);
    *(float4*)&tmp[r][4*zq] = a;
  }
  __syncthreads();                              // Hl reads done -> reuse as ww
  float (*ww)[68] = Hl;
  #pragma unroll
  for (int ii = 0; ii < 4; ++ii) {              // ww = tmp^T tmp
    const int zi = 4*tq + ii;
    float4 a = make_float4(0.f,0.f,0.f,0.f);
    for (int r = 0; r < 64; ++r) fma4(a, tmp[r][zi], *(const float4*)&tmp[r][4*zq]);
    *(float4*)&ww[zi][4*zq] = a;
  }
  if (tid < 64) {                               // wh = tmp^T y
    float acc = 0.f;
    for (int r = 0; r < 64; ++r) acc += tmp[r][tid]*yl[r];
    wh[tid] = acc;
  }
  __syncthreads();
  for (int itr = 0; itr < 10; ++itr) {          // z += 2e-6*(wh - ww@z)
    float nz = 0.f;
    if (tid < 64) {
      float mv = 0.f;
      for (int k2 = 0; k2 < 64; ++k2) mv += ww[tid][k2]*zv[k2];
      nz = zv[tid] + 2e-6f*(wh[tid] - mv);
    }
    __syncthreads();
    if (tid < 64) zv[tid] = nz;
    __syncthreads();
  }
  if (tid < 64) {                               // out = wx @ z
    float o = 0.f;
    for (int z2 = 0; z2 < 64; ++z2) o += wx[tid][z2]*zv[z2];
    out[(size_t)b*64 + tid] = o;
  }
}

// ---------------------------------------------------------------------------
extern "C" void kernel_launch(void* const* d_in, const int* in_sizes, int n_in,
                              void* d_out, int out_size, void* d_ws, size_t ws_size,
                              hipStream_t stream)
{
  const float* y    = (const float*)d_in[0];
  const float* Hm   = (const float*)d_in[1];
  const float* xraw = (const float*)d_in[2];
  const float* wih  = (const float*)d_in[3];
  const float* whh  = (const float*)d_in[4];
  const float* bih  = (const float*)d_in[5];
  const float* bhh  = (const float*)d_in[6];
  const float* Wz   = (const float*)d_in[7];
  const float* Wx   = (const float*)d_in[8];
  const float* gam  = (const float*)d_in[9];
  const float* bet  = (const float*)d_in[10];
  float* out = (float*)d_out;
  float* ws  = (float*)d_ws;

  // ws layout (floats), total = 102,419,328 floats = 409.68 MB — byte-identical
  // to the PROVEN round-1 footprint. No aliasing anywhere.
  float* wxf   = ws;                        // 33,554,432
  float* wxb   = wxf + 33554432ull;         // 33,554,432
  float* z0f   = wxb + 33554432ull;         // 524,288
  float* z0b   = z0f + 524288ull;           // 524,288
  float* htyU  = z0b + 524288ull;           // 524,288  [s][b] unscaled Hty
  float* rows  = htyU + 524288ull;          // 768
  float* bnacc = rows + 768ull;             // 2,048 (spaced x16)
  float* bnac  = bnacc + 2048ull;           // 128
  short* Wgs   = (short*)(bnac + 128ull);   // 294,912 shorts
  short* W2gs  = Wgs + 294912ull;           // 65,536 shorts
  short* fragX = W2gs + 65536ull;           // 67,108,864 shorts (134 MB)

  hipMemsetAsync(bnacc, 0, 2048*sizeof(float), stream);
  k_feats <<<8192, 256, 0, stream>>>(Hm, y, fragX, htyU, bnacc);
  k_prep  <<<1412, 256, 0, stream>>>(wih, whh, Wz, Wx, Wgs, W2gs, rows);
  k_bnfin <<<1, 64, 0, stream>>>(bnacc, gam, bet, bnac);
  k_scan  <<<512, 512, 0, stream>>>(fragX, htyU, xraw, Wgs, W2gs,
                                    bih, bhh, rows, bnac, wih, wxf, z0f);
  k_gd    <<<8192, 256, 0, stream>>>(Hm, y, wxf, wxb, z0f, z0b, out);
}

// Round 6
// 1867.788 us; speedup vs baseline: 1.1644x; 1.1644x over previous
//
#include <hip/hip_runtime.h>
#include <math.h>

// Problem constants: B=8192, S=2TX=64, F=65, HID=128, 3H=384, DIMZ=64, DIRS=2
// GD_STEP=1e-6 (two_step=2e-6), GD_ITERS=10, BN_EPS=1e-5

typedef __attribute__((ext_vector_type(8))) short s8v;   // 8 x bf16 (MFMA A/B frag)
typedef __attribute__((ext_vector_type(4))) float f4v;   // MFMA C/D frag

__device__ __forceinline__ short f2bf(float x) {         // RNE float->bf16
  unsigned u = __float_as_uint(x);
  u += 0x7fffu + ((u >> 16) & 1u);
  return (short)(u >> 16);
}
__device__ __forceinline__ float bf2f(short h) {
  return __uint_as_float(((unsigned)(unsigned short)h) << 16);
}
__device__ __forceinline__ void fma4(float4& c, float a, const float4 w) {
  c.x += a*w.x; c.y += a*w.y; c.z += a*w.z; c.w += a*w.w;
}
__device__ __forceinline__ float vget(const float4& v, int i) { return ((const float*)&v)[i]; }

// async global->LDS, 16B/lane; dest is wave-uniform base (+lane*16 by HW)
__device__ __forceinline__ void gload16(const void* g, void* l) {
  __builtin_amdgcn_global_load_lds(
      (const __attribute__((address_space(1))) void*)g,
      (__attribute__((address_space(3))) void*)l, 16, 0, 0);
}

#define MFMA(A, B, C) __builtin_amdgcn_mfma_f32_16x16x32_bf16((A), (B), (C), 0, 0, 0)

// ---------------------------------------------------------------------------
// K1: per-batch HtH -> UNSCALED split-bf16 fragX (A-frag order), htyU[s][b],
// BN stat partials. fragX elem (b,s,k): tile=b>>6, mt=(b>>4)&3, chunk kt=k>>5,
// lane=(b&15)+16*((k>>3)&3), i=k&7; hi at chunk*512+lane*8+i, lo at +4096.
// ---------------------------------------------------------------------------
__global__ __launch_bounds__(256) void k_feats(
    const float* __restrict__ Hm, const float* __restrict__ y,
    short* __restrict__ fragX, float* __restrict__ htyU, float* __restrict__ bnacc)
{
  __shared__ __align__(16) float Hl[64][68];
  __shared__ float yl[64];
  __shared__ float s1[64], s2[64];
  const int b = blockIdx.x;
  const int tid = threadIdx.x;
  const float* Hb = Hm + (size_t)b*4096;
  for (int i = tid; i < 4096; i += 256) Hl[i>>6][i&63] = Hb[i];
  if (tid < 64) { yl[tid] = y[b*64+tid]; s1[tid] = 0.f; s2[tid] = 0.f; }
  __syncthreads();

  if (tid < 64) {                       // Hty channel (f=64), unscaled, [s][b]
    float acc = 0.f;
    for (int r = 0; r < 64; ++r) acc += Hl[r][tid]*yl[r];
    htyU[tid*8192 + b] = acc;
    atomicAdd(&s1[tid], acc);
    atomicAdd(&s2[tid], acc*acc);
  }
  const int tg = tid & 15, ug = tid >> 4;
  float4 acc4[4];
  acc4[0]=acc4[1]=acc4[2]=acc4[3]=make_float4(0.f,0.f,0.f,0.f);
  for (int r = 0; r < 64; ++r) {        // HtH[t=4tg+tt][u=4ug+uu]
    const float4 tv = *(const float4*)&Hl[r][4*tg];
    const float4 uv = *(const float4*)&Hl[r][4*ug];
    #pragma unroll
    for (int tt=0;tt<4;++tt) fma4(acc4[tt], vget(tv,tt), uv);
  }
  // frag-store geometry (u = 4ug..4ug+3 -> 4 consecutive shorts in one group)
  const int mt   = (b >> 4) & 3;
  const int brow = b & 15;
  const int u0   = 4*ug;
  short* fbase = fragX + (size_t)(b >> 6)*64*8192
               + (mt*2 + (u0 >> 5))*512 + (brow + 16*((u0 >> 3) & 3))*8 + (u0 & 7);
  #pragma unroll
  for (int tt=0;tt<4;++tt) {
    const int t = 4*tg+tt;              // t == seq channel s
    float sv=0.f, sq=0.f;
    short hib[4], lob[4];
    #pragma unroll
    for (int uu=0;uu<4;++uu) {
      const float v = vget(acc4[tt],uu);
      const short hi = f2bf(v);
      hib[uu] = hi; lob[uu] = f2bf(v - bf2f(hi));
      sv += v; sq += v*v;
    }
    short* dst = fbase + (size_t)t*8192;
    *(short4*)dst          = make_short4(hib[0],hib[1],hib[2],hib[3]);
    *(short4*)(dst + 4096) = make_short4(lob[0],lob[1],lob[2],lob[3]);
    sv += __shfl_down(sv,32); sq += __shfl_down(sq,32);
    sv += __shfl_down(sv,16); sq += __shfl_down(sq,16);
    if ((tid & 63) < 16) { atomicAdd(&s1[t], sv); atomicAdd(&s2[t], sq); }
  }
  __syncthreads();
  if (tid < 64) {
    atomicAdd(&bnacc[tid*16],      s1[tid]);
    atomicAdd(&bnacc[(64+tid)*16], s2[tid]);
  }
}

// ---------------------------------------------------------------------------
// K2a: BN finalize -> a[t]=gamma/sqrt(var+eps), c[t]=beta-mu*a
// ---------------------------------------------------------------------------
__global__ void k_bnfin(const float* __restrict__ bnacc, const float* __restrict__ gam,
                        const float* __restrict__ bet, float* __restrict__ bnac)
{
  const int t = threadIdx.x;
  if (t < 64) {
    const float inv = 1.f/532480.f;           // B*F = 8192*65
    const float mu  = bnacc[t*16]*inv;
    const float var = bnacc[(64+t)*16]*inv - mu*mu;
    const float a = gam[t]*rsqrtf(var + 1e-5f);
    bnac[t] = a;
    bnac[64+t] = bet[t] - mu*a;
  }
}

// ---------------------------------------------------------------------------
// K2b: split-bf16 weight images in MFMA B-frag order + wih row sums
// Wg:  [d][sp][nt(24)][kt(6)][512]  (k: 0..63=f(wih), 64..191=j(whh))
// W2g: [d][sp][nt2(8)][kt(4)][512]  (n2: 0..63=Wx row, 64..127=Wz row)
// ---------------------------------------------------------------------------
__global__ __launch_bounds__(256) void k_prep(
    const float* __restrict__ wih, const float* __restrict__ whh,
    const float* __restrict__ Wz, const float* __restrict__ Wx,
    short* __restrict__ Wg, short* __restrict__ W2g, float* __restrict__ rowsum)
{
  const int i = blockIdx.x*256 + threadIdx.x;
  if (i < 294912) {
    const int dd = i / 147456, r = i % 147456;
    const int sp = r / 73728, r2 = r % 73728;
    const int chunk = r2 / 512, e = r2 % 512;
    const int lane = e >> 3, ii = e & 7;
    const int nt = chunk / 6, kt = chunk % 6;
    const int n = nt*16 + (lane & 15);
    const int k = kt*32 + (lane >> 4)*8 + ii;
    const float v = (k < 64) ? wih[dd*24960 + n*65 + k]
                             : whh[dd*49152 + n*128 + (k - 64)];
    const short hi = f2bf(v);
    Wg[i] = sp ? f2bf(v - bf2f(hi)) : hi;
  } else if (i < 360448) {
    const int t = i - 294912;
    const int dd = t / 32768, r = t % 32768;
    const int sp = r / 16384, r2 = r % 16384;
    const int chunk = r2 / 512, e = r2 % 512;
    const int lane = e >> 3, ii = e & 7;
    const int nt2 = chunk / 4, kt = chunk % 4;
    const int n2 = nt2*16 + (lane & 15);
    const int k = kt*32 + (lane >> 4)*8 + ii;
    const float v = (n2 < 64) ? Wx[n2*256 + dd*128 + k]
                              : Wz[(n2 - 64)*256 + dd*128 + k];
    const short hi = f2bf(v);
    W2g[t] = sp ? f2bf(v - bf2f(hi)) : hi;
  } else if (i < 361216) {
    const int t = i - 360448;
    const int dd = t / 384, g = t % 384;
    float ssum = 0.f;
    for (int f = 0; f < 65; ++f) ssum += wih[dd*24960 + g*65 + f];
    rowsum[t] = ssum;
  }
}

// ---------------------------------------------------------------------------
// K3: GRU scan. ROUND-6: WEIGHT STREAMING (de-registration).
// Diagnosis: occupancy pinned at 8 waves/CU in ALL rounds (even with 72KB LDS
// + grid 512) => register-capped: reported VGPR=128 is arch-only; ~176
// persistent weight-fragment regs live in AGPRs (unified file) => ~256
// total/wave => 2 waves/SIMD, AND zero scheduling slack (chains serialized,
// per-MFMA wall ~195 cyc in rounds 4+5, work-proportional).
// Fix: weights are loop-invariant L2-resident (720KB shared by all blocks) —
// stream them per step via a LICM-defeating laundered offset (normal IR loads
// => compiler manages waitcnts). kt-outer/mtl-inner loads each fragment once
// per step (44 x dwordx4/wave/step ≈ 12 TB/s aggregate from L2, within
// budget). Per-chain MFMA accumulation order unchanged => bitwise-identical.
// __launch_bounds__(512,4): cap 128 total regs/wave => 16 waves/CU =
// 2 co-resident blocks (LDS 2x72=144KB fits) + scheduler slack for ILP.
// ---------------------------------------------------------------------------
__global__ __launch_bounds__(512, 4) void k_scan(
    const short* __restrict__ fragX, const float* __restrict__ htyU,
    const float* __restrict__ xraw,
    const short* __restrict__ Wg, const short* __restrict__ W2g,
    const float* __restrict__ bih, const float* __restrict__ bhh,
    const float* __restrict__ rowsum, const float* __restrict__ bnac,
    const float* __restrict__ wih,
    float* __restrict__ wx_out, float* __restrict__ z0_out)
{
  __shared__ __align__(16) short Axb[8192];   // 2 x [sp(2)][mtl(2)][kt(2)][512]
  __shared__ __align__(16) short Ahb[16384];  // 2 x [sp(2)][mtl(2)][kth(4)][512]
  __shared__ __align__(16) float xl[64][36];  // 2*xraw-3, [s][b_local(32)+pad]
  __shared__ __align__(16) float gcl[1536];   // per-j consts: [j(128)][12]
  __shared__ __align__(16) float z0l[32][68]; // z0 accum [b_local][col]
  __shared__ float bna[128];

  const int tid = threadIdx.x;
  const int l   = tid & 63;
  const int w   = __builtin_amdgcn_readfirstlane(tid >> 6);   // wave 0..7
  const int tile = blockIdx.x >> 1, d = blockIdx.x & 1;       // tile 0..255
  const int b0  = tile * 32;
  const int T64 = tile >> 1, hh = tile & 1;                   // 64-tile, half
  const int l15 = l & 15, lq = l >> 4;
  const int j   = 16*w + l15;                 // this lane's hidden unit
  const int zcol = 16*(w & 3) + l15;          // z0 col for waves 4-7

  const short* Wgd = Wg  + d*147456;
  const short* W2d = W2g + d*32768;
  float* wxo = wx_out + (size_t)d * (8192ull*4096ull);
  float* z0o = z0_out + (size_t)d * (8192ull*64ull);

  // per-wave weight base offsets (elements). Gate chunk (g,sp,kt):
  //   wbG + g*24576 + sp*73728 + kt*512 ; proj chunk (sp,kt): wbP + sp*16384 + kt*512
  const int wbG = w*3072 + l*8;
  const int wbP = w*2048 + l*8;

  // h-write geometry: value (m16=lq*4+e in mtl group, col j) -> A-frag slot
  const int hw_base = (j >> 5)*512 + ((j >> 3) & 3)*128 + (j & 7);

  // this wave's staging chunk: w -> (sp, mtl, kt); byte offset inside fragX[s]
  const int c_sp  = w >> 2, c_mtl = (w >> 1) & 1, c_kt = w & 1;
  const size_t choff = (size_t)c_sp*8192 + (size_t)(2*(2*hh + c_mtl) + c_kt)*1024;
  const char* fragT = (const char*)fragX + (size_t)T64*1048576ull;

  // ---- one-time LDS preloads ----
  for (int i = tid; i < 16384; i += 512) Ahb[i] = 0;
  for (int i = tid; i < 2048; i += 512) {       // coalesced: s fastest
    const int bl = i >> 6, s = i & 63;
    xl[s][bl] = 2.f*xraw[(size_t)(b0 + bl)*64 + s] - 3.f;   // 2x - 2^RATE + 1
  }
  if (tid < 128) {                              // gate-constant table (once)
    const int jj = tid;
    float* g = &gcl[jj*12];
    g[0] = rowsum[d*384 + jj];
    g[1] = rowsum[d*384 + 128 + jj];
    g[2] = rowsum[d*384 + 256 + jj];
    g[3] = bih[d*384 + jj]       + bhh[d*384 + jj];
    g[4] = bih[d*384 + 128 + jj] + bhh[d*384 + 128 + jj];
    g[5] = bih[d*384 + 256 + jj];
    g[6] = bhh[d*384 + 256 + jj];
    g[7] = wih[d*24960 + jj*65 + 64];           // f=64 (Hty) column weights
    g[8] = wih[d*24960 + (128 + jj)*65 + 64];
    g[9] = wih[d*24960 + (256 + jj)*65 + 64];
    g[10] = 0.f; g[11] = 0.f;
  }
  for (int i = tid; i < 32*68; i += 512) ((float*)z0l)[i] = 0.f;
  if (tid < 128) bna[tid] = bnac[tid];

  f4v hprev[2];
  hprev[0] = (f4v)0.f; hprev[1] = (f4v)0.f;

  {   // prologue: Ax(s_first) -> buffer 0 (each wave loads its 1KB chunk)
    const int s0 = d ? 63 : 0;
    gload16(fragT + (size_t)s0*16384 + choff + l*16, (char*)Axb + w*1024);
  }
  __syncthreads();

  for (int it = 0; it < 64; ++it) {
    const int s  = d ? 63 - it : it;
    const int sn = (it < 63) ? (d ? s - 1 : s + 1) : s;

    // LICM-defeating laundered offset: weight loads below cannot be hoisted
    // out of the loop (they stay normal IR loads -> compiler-managed waits).
    int lz = 0;
    asm volatile("" : "+v"(lz));
    const short* Wv  = Wgd + lz;
    const short* W2v = W2d + lz;

    const short* AxR = Axb + ((it & 1) << 12);        // X(s)   : read (4096 sh)
    char*        AxW = (char*)Axb + (((it + 1) & 1) << 13);   // X(s+1) fill
    const short* AhR = Ahb + (((it + 1) & 1) << 13);  // h(s-1) : read (8192 sh)
    short*       AhW = Ahb + ((it & 1) << 13);        // h(s)   : write + proj

    // async prefetch next step's Ax chunk (drained by this step's barrier)
    gload16(fragT + (size_t)sn*16384 + choff + l*16, AxW + w*1024);

    // per-step constants (volatile LDS reads: kept out of persistent regs)
    const float a_s = bna[s], c_s = bna[64 + s];
    const volatile float* gj = gcl + j*12;
    const float crK  = c_s*gj[0] + gj[3];
    const float czK  = c_s*gj[1] + gj[4];
    const float cnK  = c_s*gj[2] + gj[5];
    const float BHN  = gj[6];
    const float w64r = gj[7], w64z = gj[8], w64n = gj[9];

    // Hty rank-1 operands (L2-resident), issued early
    const float4 hty0 = *(const float4*)&htyU[s*8192 + b0 + lq*4];
    const float4 hty1 = *(const float4*)&htyU[s*8192 + b0 + 16 + lq*4];

    // ---- gate GEMM: kt-outer (stream weights once), mtl-inner ----
    f4v Crx[2], Czx[2], Cnx[2], Crh[2], Czh[2], Cnh[2];
    #pragma unroll
    for (int m = 0; m < 2; ++m) {
      Crx[m]=(f4v)0.f; Czx[m]=(f4v)0.f; Cnx[m]=(f4v)0.f;
      Crh[m]=(f4v)0.f; Czh[m]=(f4v)0.f; Cnh[m]=(f4v)0.f;
    }
    #pragma unroll
    for (int kt = 0; kt < 6; ++kt) {
      const s8v bRh = *(const s8v*)&Wv[wbG + kt*512];
      const s8v bRl = *(const s8v*)&Wv[wbG + 73728 + kt*512];
      const s8v bZh = *(const s8v*)&Wv[wbG + 24576 + kt*512];
      const s8v bZl = *(const s8v*)&Wv[wbG + 98304 + kt*512];
      const s8v bNh = *(const s8v*)&Wv[wbG + 49152 + kt*512];
      const s8v bNl = *(const s8v*)&Wv[wbG + 122880 + kt*512];
      if (kt < 2) {
        #pragma unroll
        for (int m = 0; m < 2; ++m) {
          const s8v ah = *(const s8v*)&AxR[m*1024 + kt*512 + l*8];
          const s8v al = *(const s8v*)&AxR[2048 + m*1024 + kt*512 + l*8];
          Crx[m]=MFMA(ah,bRh,Crx[m]); Crx[m]=MFMA(ah,bRl,Crx[m]); Crx[m]=MFMA(al,bRh,Crx[m]);
          Czx[m]=MFMA(ah,bZh,Czx[m]); Czx[m]=MFMA(ah,bZl,Czx[m]); Czx[m]=MFMA(al,bZh,Czx[m]);
          Cnx[m]=MFMA(ah,bNh,Cnx[m]); Cnx[m]=MFMA(ah,bNl,Cnx[m]); Cnx[m]=MFMA(al,bNh,Cnx[m]);
        }
      } else {
        const int kh = kt - 2;
        #pragma unroll
        for (int m = 0; m < 2; ++m) {
          const s8v ah = *(const s8v*)&AhR[m*2048 + kh*512 + l*8];
          const s8v al = *(const s8v*)&AhR[4096 + m*2048 + kh*512 + l*8];
          Crh[m]=MFMA(ah,bRh,Crh[m]); Crh[m]=MFMA(ah,bRl,Crh[m]); Crh[m]=MFMA(al,bRh,Crh[m]);
          Czh[m]=MFMA(ah,bZh,Czh[m]); Czh[m]=MFMA(ah,bZl,Czh[m]); Czh[m]=MFMA(al,bZh,Czh[m]);
          Cnh[m]=MFMA(ah,bNh,Cnh[m]); Cnh[m]=MFMA(ah,bNl,Cnh[m]); Cnh[m]=MFMA(al,bNh,Cnh[m]);
        }
      }
    }

    // ---- gates epilogue + h update (numerics identical to prior rounds) ----
    #pragma unroll
    for (int m = 0; m < 2; ++m) {
      const float4 av4 = m ? hty1 : hty0;
      f4v av; av[0]=av4.x; av[1]=av4.y; av[2]=av4.z; av[3]=av4.w;
      const f4v crx = Crx[m] + av * w64r;
      const f4v czx = Czx[m] + av * w64z;
      const f4v cnx = Cnx[m] + av * w64n;
      #pragma unroll
      for (int e = 0; e < 4; ++e) {
        const float rr  = 1.f/(1.f + __expf(-(a_s*crx[e] + Crh[m][e] + crK)));
        const float zz  = 1.f/(1.f + __expf(-(a_s*czx[e] + Czh[m][e] + czK)));
        const float pre = a_s*cnx[e] + cnK + rr*(Cnh[m][e] + BHN);
        const float ax2 = fabsf(pre);
        const float ee  = __expf(-2.f*ax2);
        const float nn  = copysignf((1.f - ee)/(1.f + ee), pre);
        hprev[m][e] = (1.f - zz)*nn + zz*hprev[m][e];
      }
    }

    // write h(s) hi/lo into AhW (double-buffered: no read-drain needed)
    #pragma unroll
    for (int m = 0; m < 2; ++m)
      #pragma unroll
      for (int e = 0; e < 4; ++e) {
        const float hv = hprev[m][e];
        const short hi = f2bf(hv);
        const int ad = m*2048 + hw_base + (lq*4 + e)*8;
        AhW[ad] = hi;
        AhW[4096 + ad] = f2bf(hv - bf2f(hi));
      }
    __syncthreads();   // ONE barrier/step: h(s) + async Ax(s+1) visible

    // ---- projection: stream BP weights; waves 0-3 -> wx, 4-7 -> z0l ----
    f4v Cp[2]; Cp[0] = (f4v)0.f; Cp[1] = (f4v)0.f;
    #pragma unroll
    for (int kt = 0; kt < 4; ++kt) {
      const s8v bPh = *(const s8v*)&W2v[wbP + kt*512];
      const s8v bPl = *(const s8v*)&W2v[wbP + 16384 + kt*512];
      #pragma unroll
      for (int m = 0; m < 2; ++m) {
        const s8v ah = *(const s8v*)&AhW[m*2048 + kt*512 + l*8];
        const s8v al = *(const s8v*)&AhW[4096 + m*2048 + kt*512 + l*8];
        Cp[m]=MFMA(ah,bPh,Cp[m]); Cp[m]=MFMA(ah,bPl,Cp[m]); Cp[m]=MFMA(al,bPh,Cp[m]);
      }
    }
    #pragma unroll
    for (int m = 0; m < 2; ++m) {
      if (w < 4) {
        #pragma unroll
        for (int e = 0; e < 4; ++e)
          wxo[(size_t)(b0 + m*16 + lq*4 + e)*4096 + s*64 + 16*w + l15] = Cp[m][e];
      } else {
        #pragma unroll
        for (int e = 0; e < 4; ++e) {
          const int bl = m*16 + lq*4 + e;
          z0l[bl][zcol] += xl[s][bl] * Cp[m][e];  // LDS RMW, cols disjoint/wave
        }
      }
    }
  }
  if (w >= 4) {
    #pragma unroll
    for (int m = 0; m < 2; ++m)
      #pragma unroll
      for (int e = 0; e < 4; ++e) {
        const int bl = m*16 + lq*4 + e;
        z0o[(size_t)(b0 + bl)*64 + zcol] = z0l[bl][zcol];
      }
  }
}

// ---------------------------------------------------------------------------
// K4: GD loop via Gram trick: tmp=H@wx; ww=tmp^T tmp; wh=tmp^T y (no HtH).
// ---------------------------------------------------------------------------
__global__ __launch_bounds__(256) void k_gd(
    const float* __restrict__ Hm, const float* __restrict__ y,
    const float* __restrict__ wxf, const float* __restrict__ wxb,
    const float* __restrict__ z0f, const float* __restrict__ z0b,
    float* __restrict__ out)
{
  __shared__ __align__(16) float Hl[64][68];    // H[r][t]; reused as ww[zi][zj]
  __shared__ __align__(16) float wx[64][68];    // wx[s][z]
  __shared__ __align__(16) float tmp[64][68];   // (H@wx)[r][z]
  __shared__ float yl[64], wh[64], zv[64];
  const int b = blockIdx.x;
  const int tid = threadIdx.x;
  const float* Hb = Hm + (size_t)b*4096;
  for (int i = tid; i < 4096; i += 256) {
    Hl[i>>6][i&63] = Hb[i];
    wx[i>>6][i&63] = wxf[(size_t)b*4096 + i] + wxb[(size_t)b*4096 + i];
  }
  if (tid < 64) {
    yl[tid] = y[b*64+tid];
    zv[tid] = z0f[(size_t)b*64+tid] + z0b[(size_t)b*64+tid];
  }
  __syncthreads();
  const int zq = tid & 15, tq = tid >> 4;
  #pragma unroll
  for (int rr = 0; rr < 4; ++rr) {             // tmp = H @ wx
    const int r = 4*tq + rr;
    float4 a = make_float4(0.f,0.f,0.f,0.f);
    for (int t = 0; t < 64; ++t) fma4(a, Hl[r][t], *(const float4*)&wx[t][4*zq]);
    *(float4*)&tmp[r][4*zq] = a;
  }
  __syncthreads();                              // Hl reads done -> reuse as ww
  float (*ww)[68] = Hl;
  #pragma unroll
  for (int ii = 0; ii < 4; ++ii) {              // ww = tmp^T tmp
    const int zi = 4*tq + ii;
    float4 a = make_float4(0.f,0.f,0.f,0.f);
    for (int r = 0; r < 64; ++r) fma4(a, tmp[r][zi], *(const float4*)&tmp[r][4*zq]);
    *(float4*)&ww[zi][4*zq] = a;
  }
  if (tid < 64) {                               // wh = tmp^T y
    float acc = 0.f;
    for (int r = 0; r < 64; ++r) acc += tmp[r][tid]*yl[r];
    wh[tid] = acc;
  }
  __syncthreads();
  for (int itr = 0; itr < 10; ++itr) {          // z += 2e-6*(wh - ww@z)
    float nz = 0.f;
    if (tid < 64) {
      float mv = 0.f;
      for (int k2 = 0; k2 < 64; ++k2) mv += ww[tid][k2]*zv[k2];
      nz = zv[tid] + 2e-6f*(wh[tid] - mv);
    }
    __syncthreads();
    if (tid < 64) zv[tid] = nz;
    __syncthreads();
  }
  if (tid < 64) {                               // out = wx @ z
    float o = 0.f;
    for (int z2 = 0; z2 < 64; ++z2) o += wx[tid][z2]*zv[z2];
    out[(size_t)b*64 + tid] = o;
  }
}

// ---------------------------------------------------------------------------
extern "C" void kernel_launch(void* const* d_in, const int* in_sizes, int n_in,
                              void* d_out, int out_size, void* d_ws, size_t ws_size,
                              hipStream_t stream)
{
  const float* y    = (const float*)d_in[0];
  const float* Hm   = (const float*)d_in[1];
  const float* xraw = (const float*)d_in[2];
  const float* wih  = (const float*)d_in[3];
  const float* whh  = (const float*)d_in[4];
  const float* bih  = (const float*)d_in[5];
  const float* bhh  = (const float*)d_in[6];
  const float* Wz   = (const float*)d_in[7];
  const float* Wx   = (const float*)d_in[8];
  const float* gam  = (const float*)d_in[9];
  const float* bet  = (const float*)d_in[10];
  float* out = (float*)d_out;
  float* ws  = (float*)d_ws;

  // ws layout (floats), total = 102,419,328 floats = 409.68 MB — byte-identical
  // to the PROVEN round-1 footprint. No aliasing anywhere.
  float* wxf   = ws;                        // 33,554,432
  float* wxb   = wxf + 33554432ull;         // 33,554,432
  float* z0f   = wxb + 33554432ull;         // 524,288
  float* z0b   = z0f + 524288ull;           // 524,288
  float* htyU  = z0b + 524288ull;           // 524,288  [s][b] unscaled Hty
  float* rows  = htyU + 524288ull;          // 768
  float* bnacc = rows + 768ull;             // 2,048 (spaced x16)
  float* bnac  = bnacc + 2048ull;           // 128
  short* Wgs   = (short*)(bnac + 128ull);   // 294,912 shorts
  short* W2gs  = Wgs + 294912ull;           // 65,536 shorts
  short* fragX = W2gs + 65536ull;           // 67,108,864 shorts (134 MB)

  hipMemsetAsync(bnacc, 0, 2048*sizeof(float), stream);
  k_feats <<<8192, 256, 0, stream>>>(Hm, y, fragX, htyU, bnacc);
  k_prep  <<<1412, 256, 0, stream>>>(wih, whh, Wz, Wx, Wgs, W2gs, rows);
  k_bnfin <<<1, 64, 0, stream>>>(bnacc, gam, bet, bnac);
  k_scan  <<<512, 512, 0, stream>>>(fragX, htyU, xraw, Wgs, W2gs,
                                    bih, bhh, rows, bnac, wih, wxf, z0f);
  k_gd    <<<8192, 256, 0, stream>>>(Hm, y, wxf, wxb, z0f, z0b, out);
}